// Round 6
// baseline (907.504 us; speedup 1.0000x reference)
//
#include <hip/hip_runtime.h>
#include <stdint.h>

// Problem constants (B=4,S=2048 -> T=8192 tokens). Inputs fp32, OUTPUT fp32.
#define T_TOK 8192
#define DDIM  2048
#define NEXP  8
#define FDIM  1024
#define CAP   25600   // 16384 assignments + 8*128 pad + 8192 shared rows
#define NT_M  200     // CAP/128 M-tiles (fixed grid; blocks beyond off[9] exit)
#define BK    64
#define LDA   72      // padded LDS row stride (elements); 144B keeps 16B alignment

typedef __bf16 bf16x8 __attribute__((ext_vector_type(8)));
typedef float  f32x4  __attribute__((ext_vector_type(4)));

__device__ __forceinline__ float bf2f(uint16_t u) {
  union { uint32_t i; float f; } v; v.i = ((uint32_t)u) << 16; return v.f;
}
__device__ __forceinline__ uint16_t f2bf(float f) {
  union { float f; uint32_t i; } v; v.f = f;
  uint32_t i = v.i;
  i += 0x7FFFu + ((i >> 16) & 1u);   // RNE
  return (uint16_t)(i >> 16);
}

// ---------------------------------------------------------------------------
// K1: RMSNorm + router, all fp32. h stored as bf16 (MFMA operand).
// ---------------------------------------------------------------------------
__global__ __launch_bounds__(256) void k_rms_router(
    const float* __restrict__ x, const float* __restrict__ rmsw,
    const float* __restrict__ router_w, uint16_t* __restrict__ h,
    int* __restrict__ topi, float* __restrict__ topw, int* __restrict__ counts)
{
  int t = blockIdx.x, tid = threadIdx.x;
  int lane = tid & 63, wv = tid >> 6;
  const float* xr = x + (size_t)t * DDIM;
  float4 x0 = ((const float4*)xr)[tid * 2];
  float4 x1 = ((const float4*)xr)[tid * 2 + 1];
  float4 w0 = ((const float4*)rmsw)[tid * 2];
  float4 w1 = ((const float4*)rmsw)[tid * 2 + 1];
  float xv[8] = {x0.x, x0.y, x0.z, x0.w, x1.x, x1.y, x1.z, x1.w};
  float wv8[8] = {w0.x, w0.y, w0.z, w0.w, w1.x, w1.y, w1.z, w1.w};
  float ss = 0.f;
  #pragma unroll
  for (int j = 0; j < 8; j++) ss += xv[j] * xv[j];
  #pragma unroll
  for (int m = 32; m >= 1; m >>= 1) ss += __shfl_xor(ss, m, 64);
  __shared__ float rs[4];
  __shared__ float sscale;
  if (lane == 0) rs[wv] = ss;
  __syncthreads();
  if (tid == 0) sscale = rsqrtf((rs[0] + rs[1] + rs[2] + rs[3]) * (1.0f / DDIM) + 1e-6f);
  __syncthreads();
  float scale = sscale;
  float hv[8];
  #pragma unroll
  for (int j = 0; j < 8; j++) hv[j] = xv[j] * scale * wv8[j];
  ushort4 h0, h1;
  h0.x = f2bf(hv[0]); h0.y = f2bf(hv[1]); h0.z = f2bf(hv[2]); h0.w = f2bf(hv[3]);
  h1.x = f2bf(hv[4]); h1.y = f2bf(hv[5]); h1.z = f2bf(hv[6]); h1.w = f2bf(hv[7]);
  ((ushort4*)(h + (size_t)t * DDIM))[tid * 2]     = h0;
  ((ushort4*)(h + (size_t)t * DDIM))[tid * 2 + 1] = h1;

  float lp[8] = {0, 0, 0, 0, 0, 0, 0, 0};
  const float* rwm = router_w + (size_t)tid * 8 * NEXP;
  #pragma unroll
  for (int j = 0; j < 8; j++) {
    float4 a = ((const float4*)(rwm + j * NEXP))[0];
    float4 b = ((const float4*)(rwm + j * NEXP))[1];
    float hj = hv[j];
    lp[0] += hj * a.x; lp[1] += hj * a.y; lp[2] += hj * a.z; lp[3] += hj * a.w;
    lp[4] += hj * b.x; lp[5] += hj * b.y; lp[6] += hj * b.z; lp[7] += hj * b.w;
  }
  #pragma unroll
  for (int m = 32; m >= 1; m >>= 1) {
    #pragma unroll
    for (int e = 0; e < 8; e++) lp[e] += __shfl_xor(lp[e], m, 64);
  }
  __shared__ float rl[4][8];
  if (lane == 0) {
    #pragma unroll
    for (int e = 0; e < 8; e++) rl[wv][e] = lp[e];
  }
  __syncthreads();
  if (tid == 0) {
    float lg[8];
    #pragma unroll
    for (int e = 0; e < 8; e++) lg[e] = rl[0][e] + rl[1][e] + rl[2][e] + rl[3][e];
    int i0 = 0;
    for (int e = 1; e < 8; e++) if (lg[e] > lg[i0]) i0 = e;   // earliest max
    int i1 = (i0 == 0) ? 1 : 0;
    for (int e = 0; e < 8; e++) if (e != i0 && lg[e] > lg[i1]) i1 = e;
    float p0 = 1.f / (1.f + expf(lg[i1] - lg[i0]));  // renormalized top-2
    topi[t * 2] = i0; topi[t * 2 + 1] = i1;
    topw[t * 2] = p0; topw[t * 2 + 1] = 1.f - p0;
    atomicAdd(&counts[i0], 1);
    atomicAdd(&counts[i1], 1);
  }
}

// ---------------------------------------------------------------------------
__global__ void k_offsets(const int* __restrict__ counts, int* __restrict__ off) {
  if (threadIdx.x == 0 && blockIdx.x == 0) {
    int o = 0;
    for (int e = 0; e < NEXP; e++) { off[e] = o; o += (counts[e] + 127) & ~127; }
    off[8] = o;
    off[9] = o + T_TOK;
  }
}

// ---------------------------------------------------------------------------
__global__ __launch_bounds__(256) void k_scatter(
    const int* __restrict__ topi, const float* __restrict__ topw,
    const int* __restrict__ off, int* __restrict__ cursor,
    int* __restrict__ tokslot, float* __restrict__ wtrow)
{
  int idx = blockIdx.x * 256 + threadIdx.x;   // 0..24575
  if (idx < T_TOK * 2) {
    int t = idx >> 1, k = idx & 1;
    int e = topi[idx];
    int slot = atomicAdd(&cursor[e], 1);
    int row = off[e] + slot;
    tokslot[row] = t * 4 + k;
    wtrow[row] = topw[idx];
  } else {
    int t = idx - T_TOK * 2;
    int row = off[8] + t;
    tokslot[row] = t * 4 + 2;
    wtrow[row] = 1.0f;
  }
}

// ---------------------------------------------------------------------------
// K4: tiled convert-transpose fp32 [R][C] -> bf16 [C][R], batched over z.
// ---------------------------------------------------------------------------
__global__ __launch_bounds__(256) void k_transpose_cvt(
    const float* __restrict__ src, uint16_t* __restrict__ dst, int R, int C)
{
  __shared__ float tile[32][33];
  size_t mb = (size_t)blockIdx.z * R * C;
  int c0 = blockIdx.x * 32, r0 = blockIdx.y * 32;
  int tx = threadIdx.x & 31, ty = threadIdx.x >> 5;  // 32x8
  #pragma unroll
  for (int i = 0; i < 4; i++)
    tile[ty + 8 * i][tx] = src[mb + (size_t)(r0 + ty + 8 * i) * C + c0 + tx];
  __syncthreads();
  #pragma unroll
  for (int i = 0; i < 4; i++)
    dst[mb + (size_t)(c0 + ty + 8 * i) * R + r0 + tx] = f2bf(tile[tx][ty + 8 * i]);
}

// ---------------------------------------------------------------------------
// K5: stage-1 grouped GEMM: A_int = silu(H W_gate) * (H W_up)  (bf16 MFMA)
// Reg-staged ds_write path, LDA=72 pad. 128 rows x 64 f-cols, 4 waves (2x2).
// ---------------------------------------------------------------------------
__global__ __launch_bounds__(256) void k_stage1(
    const uint16_t* __restrict__ h, const uint16_t* __restrict__ wgT,
    const uint16_t* __restrict__ wuT, const uint16_t* __restrict__ sgT,
    const uint16_t* __restrict__ suT, const int* __restrict__ off,
    const int* __restrict__ tokslot, uint16_t* __restrict__ A_int)
{
  __shared__ __align__(16) uint16_t sA[128 * LDA];
  __shared__ __align__(16) uint16_t sG[64 * LDA];
  __shared__ __align__(16) uint16_t sU[64 * LDA];

  int row0 = blockIdx.x * 128;
  int end = off[9];
  if (row0 >= end) return;
  int e = 0;
  #pragma unroll 1
  for (; e < 9; e++) if (row0 >= off[e] && row0 < off[e + 1]) break;
  const uint16_t* bg = (e < NEXP) ? wgT + (size_t)e * FDIM * DDIM : sgT;
  const uint16_t* bu = (e < NEXP) ? wuT + (size_t)e * FDIM * DDIM : suT;
  int f0 = blockIdx.y * 64;

  int tid = threadIdx.x, lane = tid & 63, w = tid >> 6;

  const uint16_t* srcA[4]; uint16_t* dstA[4];
  #pragma unroll
  for (int i = 0; i < 4; i++) {
    int G = w * 256 + i * 64 + lane;        // 0..1023 (128 rows x 8 slots)
    int r = G >> 3, sl = G & 7;
    int ts = tokslot[row0 + r];
    int tok = ts < 0 ? 0 : (ts >> 2);       // padded rows: token 0 (discarded)
    srcA[i] = h + (size_t)tok * DDIM + sl * 8;
    dstA[i] = sA + r * LDA + sl * 8;
  }
  const uint16_t* srcGp[2]; const uint16_t* srcUp[2];
  uint16_t* dstGp[2]; uint16_t* dstUp[2];
  #pragma unroll
  for (int i = 0; i < 2; i++) {
    int G = w * 128 + i * 64 + lane;        // 0..511 (64 rows x 8 slots)
    int r = G >> 3, sl = G & 7;
    srcGp[i] = bg + (size_t)(f0 + r) * DDIM + sl * 8;
    srcUp[i] = bu + (size_t)(f0 + r) * DDIM + sl * 8;
    dstGp[i] = sG + r * LDA + sl * 8;
    dstUp[i] = sU + r * LDA + sl * 8;
  }

  f32x4 accg[4][2] = {};
  f32x4 accu[4][2] = {};

  for (int kt = 0; kt < DDIM; kt += BK) {
    uint4 va[4], vg[2], vu[2];
    #pragma unroll
    for (int i = 0; i < 4; i++) va[i] = *(const uint4*)(srcA[i] + kt);
    #pragma unroll
    for (int i = 0; i < 2; i++) {
      vg[i] = *(const uint4*)(srcGp[i] + kt);
      vu[i] = *(const uint4*)(srcUp[i] + kt);
    }
    #pragma unroll
    for (int i = 0; i < 4; i++) *(uint4*)dstA[i] = va[i];
    #pragma unroll
    for (int i = 0; i < 2; i++) {
      *(uint4*)dstGp[i] = vg[i];
      *(uint4*)dstUp[i] = vu[i];
    }
    __syncthreads();
    #pragma unroll
    for (int ks = 0; ks < 2; ks++) {
      int ce = ks * 32 + ((lane >> 4) << 3);   // element offset in K-tile
      bf16x8 av[4], gv[2], uv[2];
      #pragma unroll
      for (int m = 0; m < 4; m++) {
        int rr = (w & 1) * 64 + m * 16 + (lane & 15);
        av[m] = *(const bf16x8*)(sA + rr * LDA + ce);
      }
      #pragma unroll
      for (int n = 0; n < 2; n++) {
        int rr = (w >> 1) * 32 + n * 16 + (lane & 15);
        gv[n] = *(const bf16x8*)(sG + rr * LDA + ce);
        uv[n] = *(const bf16x8*)(sU + rr * LDA + ce);
      }
      #pragma unroll
      for (int m = 0; m < 4; m++) {
        #pragma unroll
        for (int n = 0; n < 2; n++) {
          accg[m][n] = __builtin_amdgcn_mfma_f32_16x16x32_bf16(av[m], gv[n], accg[m][n], 0, 0, 0);
          accu[m][n] = __builtin_amdgcn_mfma_f32_16x16x32_bf16(av[m], uv[n], accu[m][n], 0, 0, 0);
        }
      }
    }
    __syncthreads();
  }

  // epilogue: silu(g)*u -> bf16 A_int
  int wr = (w & 1) * 64, wc = (w >> 1) * 32;
  #pragma unroll
  for (int m = 0; m < 4; m++) {
    #pragma unroll
    for (int n = 0; n < 2; n++) {
      #pragma unroll
      for (int r = 0; r < 4; r++) {
        int row = row0 + wr + m * 16 + ((lane >> 4) << 2) + r;
        int col = f0 + wc + n * 16 + (lane & 15);
        float g = accg[m][n][r], u = accu[m][n][r];
        float a = (g / (1.f + expf(-g))) * u;
        A_int[(size_t)row * FDIM + col] = f2bf(a);
      }
    }
  }
}

// ---------------------------------------------------------------------------
// K6: stage-2 grouped GEMM: EO = A_int @ W_down.
// Routed rows: fp32*weight -> eo_r[tok][slot][*]. Shared rows: fp32 -> out.
// Block: 128 rows x 128 d-cols, BK=64, 4 waves (2x2) each 64x64.
// ---------------------------------------------------------------------------
__global__ __launch_bounds__(256) void k_stage2(
    const uint16_t* __restrict__ A_int, const uint16_t* __restrict__ wdT,
    const uint16_t* __restrict__ sdT, const int* __restrict__ off,
    const int* __restrict__ tokslot, const float* __restrict__ wtrow,
    float* __restrict__ eo_r, float* __restrict__ out)
{
  __shared__ __align__(16) uint16_t sA[128 * LDA];
  __shared__ __align__(16) uint16_t sB[128 * LDA];

  int row0 = blockIdx.x * 128;
  int end = off[9];
  if (row0 >= end) return;
  int e = 0;
  #pragma unroll 1
  for (; e < 9; e++) if (row0 >= off[e] && row0 < off[e + 1]) break;
  const uint16_t* bw = (e < NEXP) ? wdT + (size_t)e * DDIM * FDIM : sdT;
  int d0 = blockIdx.y * 128;

  int tid = threadIdx.x, lane = tid & 63, w = tid >> 6;

  const uint16_t* srcA[4]; const uint16_t* srcB[4];
  uint16_t* dstA[4]; uint16_t* dstB[4];
  #pragma unroll
  for (int i = 0; i < 4; i++) {
    int G = w * 256 + i * 64 + lane;
    int r = G >> 3, sl = G & 7;
    srcA[i] = A_int + (size_t)(row0 + r) * FDIM + sl * 8;
    srcB[i] = bw + (size_t)(d0 + r) * FDIM + sl * 8;
    dstA[i] = sA + r * LDA + sl * 8;
    dstB[i] = sB + r * LDA + sl * 8;
  }

  f32x4 acc[4][4] = {};

  for (int kt = 0; kt < FDIM; kt += BK) {
    uint4 va[4], vb[4];
    #pragma unroll
    for (int i = 0; i < 4; i++) {
      va[i] = *(const uint4*)(srcA[i] + kt);
      vb[i] = *(const uint4*)(srcB[i] + kt);
    }
    #pragma unroll
    for (int i = 0; i < 4; i++) {
      *(uint4*)dstA[i] = va[i];
      *(uint4*)dstB[i] = vb[i];
    }
    __syncthreads();
    #pragma unroll
    for (int ks = 0; ks < 2; ks++) {
      int ce = ks * 32 + ((lane >> 4) << 3);
      bf16x8 av[4], bv[4];
      #pragma unroll
      for (int m = 0; m < 4; m++) {
        int rr = (w & 1) * 64 + m * 16 + (lane & 15);
        av[m] = *(const bf16x8*)(sA + rr * LDA + ce);
      }
      #pragma unroll
      for (int n = 0; n < 4; n++) {
        int rr = (w >> 1) * 64 + n * 16 + (lane & 15);
        bv[n] = *(const bf16x8*)(sB + rr * LDA + ce);
      }
      #pragma unroll
      for (int m = 0; m < 4; m++) {
        #pragma unroll
        for (int n = 0; n < 4; n++)
          acc[m][n] = __builtin_amdgcn_mfma_f32_16x16x32_bf16(av[m], bv[n], acc[m][n], 0, 0, 0);
      }
    }
    __syncthreads();
  }

  int wr = (w & 1) * 64, wc = (w >> 1) * 64;
  #pragma unroll
  for (int m = 0; m < 4; m++) {
    #pragma unroll
    for (int r = 0; r < 4; r++) {
      int grow = row0 + wr + m * 16 + ((lane >> 4) << 2) + r;
      int ts = tokslot[grow];
      if (ts < 0) continue;                  // padded row
      int tok = ts >> 2, slot = ts & 3;
      if (slot == 2) {                       // shared expert -> fp32 out
        size_t obase = (size_t)tok * DDIM;
        #pragma unroll
        for (int n = 0; n < 4; n++) {
          int col = d0 + wc + n * 16 + (lane & 15);
          out[obase + col] = acc[m][n][r];
        }
      } else {                               // routed -> fp32 weighted slot
        float wt = wtrow[grow];
        size_t obase = ((size_t)tok * 2 + slot) * DDIM;
        #pragma unroll
        for (int n = 0; n < 4; n++) {
          int col = d0 + wc + n * 16 + (lane & 15);
          eo_r[obase + col] = acc[m][n][r] * wt;
        }
      }
    }
  }
}

// ---------------------------------------------------------------------------
// K7: out = out_shared + eo_r[slot0] + eo_r[slot1]   (all fp32)
// ---------------------------------------------------------------------------
__global__ __launch_bounds__(256) void k_final(
    const float* __restrict__ eo_r, float* __restrict__ out)
{
  int tok = blockIdx.x;
  int col = threadIdx.x * 8;
  const float* e0 = eo_r + ((size_t)tok * 2) * DDIM + col;
  const float* e1 = eo_r + ((size_t)tok * 2 + 1) * DDIM + col;
  float* op = out + (size_t)tok * DDIM + col;
  float4 s0 = *(const float4*)(op);
  float4 s1 = *(const float4*)(op + 4);
  float4 a0 = *(const float4*)(e0);
  float4 a1 = *(const float4*)(e0 + 4);
  float4 b0 = *(const float4*)(e1);
  float4 b1 = *(const float4*)(e1 + 4);
  float4 o0, o1;
  o0.x = s0.x + a0.x + b0.x;  o0.y = s0.y + a0.y + b0.y;
  o0.z = s0.z + a0.z + b0.z;  o0.w = s0.w + a0.w + b0.w;
  o1.x = s1.x + a1.x + b1.x;  o1.y = s1.y + a1.y + b1.y;
  o1.z = s1.z + a1.z + b1.z;  o1.w = s1.w + a1.w + b1.w;
  *(float4*)(op) = o0;
  *(float4*)(op + 4) = o1;
}

// ---------------------------------------------------------------------------
extern "C" void kernel_launch(void* const* d_in, const int* in_sizes, int n_in,
                              void* d_out, int out_size, void* d_ws, size_t ws_size,
                              hipStream_t stream) {
  (void)in_sizes; (void)n_in; (void)out_size;
  const float* x    = (const float*)d_in[0];
  const float* rmsw = (const float*)d_in[1];
  const float* rtw  = (const float*)d_in[2];
  const float* wg   = (const float*)d_in[3];
  const float* wu   = (const float*)d_in[4];
  const float* wd   = (const float*)d_in[5];
  const float* sg   = (const float*)d_in[6];
  const float* su   = (const float*)d_in[7];
  const float* sd   = (const float*)d_in[8];
  float* out = (float*)d_out;   // reference output dtype is float32

  // ---- workspace layout with lifetime overlays (224.73 MB, known to fit) ----
  char* base = (char*)d_ws;
  size_t off_b = 0;
  auto place = [&](size_t bytes) { size_t r = off_b; off_b += (bytes + 255) & ~(size_t)255; return r; };
  size_t o_topi    = place((size_t)T_TOK * 2 * 4);
  size_t o_topw    = place((size_t)T_TOK * 2 * 4);
  size_t o_counts  = place(64);
  size_t o_offs    = place(64);
  size_t o_cursor  = place(64);
  size_t o_tokslot = place((size_t)CAP * 4);
  size_t o_wtrow   = place((size_t)CAP * 4);
  // eo_r: fp32 [T][2][D] (phase C/D). Overlaid by h/wgT/wuT/sgT/suT (phase A/B).
  size_t o_eor = place((size_t)T_TOK * 2 * DDIM * 4);           // 134.22 MB
  size_t o_h   = o_eor;                                         // 33.55 MB
  size_t o_wgT = o_eor + (size_t)T_TOK * DDIM * 2;              // 33.55 MB
  size_t o_wuT = o_wgT + (size_t)NEXP * FDIM * DDIM * 2;        // 33.55 MB
  size_t o_sgT = o_wuT + (size_t)NEXP * FDIM * DDIM * 2;        // 4.19 MB
  size_t o_suT = o_sgT + (size_t)FDIM * DDIM * 2;               // 4.19 MB (ends 109.05 < 134.22)
  size_t o_wdT = place((size_t)NEXP * DDIM * FDIM * 2);         // 33.55 MB
  size_t o_sdT = place((size_t)DDIM * FDIM * 2);                // 4.19 MB
  size_t o_Ai  = place((size_t)CAP * FDIM * 2);                 // 52.43 MB
  size_t NEED = off_b;
  if (ws_size < NEED) return;  // clean diagnostic instead of fault

  int*      topi    = (int*)(base + o_topi);
  float*    topw    = (float*)(base + o_topw);
  int*      counts  = (int*)(base + o_counts);
  int*      offs    = (int*)(base + o_offs);
  int*      cursor  = (int*)(base + o_cursor);
  int*      tokslot = (int*)(base + o_tokslot);
  float*    wtrow   = (float*)(base + o_wtrow);
  float*    eo_r    = (float*)(base + o_eor);
  uint16_t* h       = (uint16_t*)(base + o_h);
  uint16_t* wgT     = (uint16_t*)(base + o_wgT);
  uint16_t* wuT     = (uint16_t*)(base + o_wuT);
  uint16_t* sgT     = (uint16_t*)(base + o_sgT);
  uint16_t* suT     = (uint16_t*)(base + o_suT);
  uint16_t* wdT     = (uint16_t*)(base + o_wdT);
  uint16_t* sdT     = (uint16_t*)(base + o_sdT);
  uint16_t* Ai      = (uint16_t*)(base + o_Ai);

  hipMemsetAsync(counts, 0, 64, stream);
  hipMemsetAsync(cursor, 0, 64, stream);
  hipMemsetAsync(tokslot, 0xFF, (size_t)CAP * 4, stream);  // -1 = padded row

  // fp32 -> bf16 convert-transposes ([d][f] -> [f][d] etc.)
  k_transpose_cvt<<<dim3(FDIM / 32, DDIM / 32, NEXP), 256, 0, stream>>>(wg, wgT, DDIM, FDIM);
  k_transpose_cvt<<<dim3(FDIM / 32, DDIM / 32, NEXP), 256, 0, stream>>>(wu, wuT, DDIM, FDIM);
  k_transpose_cvt<<<dim3(DDIM / 32, FDIM / 32, NEXP), 256, 0, stream>>>(wd, wdT, FDIM, DDIM);
  k_transpose_cvt<<<dim3(FDIM / 32, DDIM / 32, 1),    256, 0, stream>>>(sg, sgT, DDIM, FDIM);
  k_transpose_cvt<<<dim3(FDIM / 32, DDIM / 32, 1),    256, 0, stream>>>(su, suT, DDIM, FDIM);
  k_transpose_cvt<<<dim3(DDIM / 32, FDIM / 32, 1),    256, 0, stream>>>(sd, sdT, FDIM, DDIM);

  k_rms_router<<<T_TOK, 256, 0, stream>>>(x, rmsw, rtw, h, topi, topw, counts);
  k_offsets<<<1, 64, 0, stream>>>(counts, offs);
  k_scatter<<<(T_TOK * 3) / 256, 256, 0, stream>>>(topi, topw, offs, cursor, tokslot, wtrow);

  k_stage1<<<dim3(NT_M, FDIM / 64), 256, 0, stream>>>(h, wgT, wuT, sgT, suT, offs, tokslot, Ai);
  // stage2 overwrites the h/wgT/wuT/sgT/suT region (now dead) as eo_r
  k_stage2<<<dim3(NT_M, DDIM / 128), 256, 0, stream>>>(Ai, wdT, sdT, offs, tokslot, wtrow, eo_r, out);
  k_final<<<T_TOK, 256, 0, stream>>>(eo_r, out);
}